// Round 2
// baseline (15064.885 us; speedup 1.0000x reference)
//
#include <hip/hip_runtime.h>
#include <math.h>

// Problem constants (EnhancedVectorQuantizer): inputs (16,4096,256) f32, emb (2048,256) f32
#define NROWS  65536
#define DIM    256
#define KCODES 2048

#define Q_OFF  16777216   // NROWS*DIM; d_out layout: [0,Q_OFF) quantized_st, [Q_OFF]=loss, [Q_OFF+1]=perplexity, [Q_OFF+2..) idx as f32

// workspace byte offsets (total 294912 B)
#define WS_C      0        // 2048 f32  ||e_k||^2
#define WS_INV    8192     // 2048 f32  1/max(rownorm,1e-12)
#define WS_COUNTS 16384    // 2048 u32
#define WS_SUMS   24576    // 3 doubles: [0]=mse_sum [1]=l2_sum [2]=orth_sum
#define WS_X2     32768    // 65536 f32 ||x_n||^2 (replaces idx_ws; gather reads idx from out)

typedef __attribute__((address_space(1))) const void gvoid_t;
typedef __attribute__((address_space(3))) void lvoid_t;

// ---------------- init: zero accumulators (ws is poisoned 0xAA every launch) ----------------
__global__ void vq_init_kernel(unsigned* __restrict__ counts, double* __restrict__ sums) {
    int t = threadIdx.x;
    for (int k = t; k < KCODES; k += 256) counts[k] = 0u;
    if (t < 3) sums[t] = 0.0;
}

// ---------------- prep: c[k]=||e_k||^2, inv rownorm, l2 sum ----------------
__global__ void vq_prep_kernel(const float* __restrict__ emb, float* __restrict__ c,
                               float* __restrict__ invn, double* __restrict__ sums) {
    int k = blockIdx.x;
    int lane = threadIdx.x;                       // 64 lanes
    float4 v = ((const float4*)(emb + (size_t)k * DIM))[lane];
    float s = v.x * v.x + v.y * v.y + v.z * v.z + v.w * v.w;
    #pragma unroll
    for (int off = 32; off > 0; off >>= 1) s += __shfl_down(s, off, 64);
    if (lane == 0) {
        c[k] = s;
        float rn = sqrtf(s);
        invn[k] = 1.0f / fmaxf(rn, 1e-12f);
        atomicAdd(&sums[1], (double)rn);
    }
}

// ---------------- x2: per-row ||x||^2, serial float4 chain (bit-identical to ref order) ----------------
__global__ void vq_x2_kernel(const float* __restrict__ x, float* __restrict__ x2g) {
    int row = blockIdx.x * 256 + threadIdx.x;
    const float4* xr = (const float4*)(x + (size_t)row * DIM);
    float s = 0.f;
    for (int d4 = 0; d4 < DIM / 4; ++d4) {
        float4 v = xr[d4];
        s += v.x * v.x; s += v.y * v.y; s += v.z * v.z; s += v.w * v.w;
    }
    x2g[row] = s;
}

// ---------------- argmin: global-broadcast A + streamed-B-in-LDS fp32 distance GEMM + argmin ----------------
// Round-8 theory: round-7's 8x8 tile fixed the LDS pipe (conflicts 1.35e8 -> 0, dur
// 1675 -> 1212us) but VALUBusy froze at 67% with Occupancy 21% (80KB LDS -> 2 blocks/CU
// = 2 waves/SIMD). Measured VALU-busy (817us) matches the bit-exact chain's instr mix,
// so the remaining 33% is latency-hiding deficit, not issue-bound work.
// Fix: A-reads are 2-address wave broadcasts -> serve them from GLOBAL (block-private
// 64KB tile, L1/L2/L3-resident; values and expression identical -> bit-exact preserved).
// LDS keeps only double-buffered B (16KB). Final argmin reduction moves to 32-lane
// shuffles (each row's 32 candidates live in one half-wave). 16KB LDS + <=128 VGPR
// (waves_per_eu(4,4)) -> 4 blocks/CU = 4 waves/SIMD: double the latency-hiding pool,
// same per-MAC VALU/LDS mix.
//   threads = 32 tx (codes, k = kt + tx + 32i) x 8 ty (rows, ty*8+j)
//   B chunk layout [g:2][256 codes][float4]: a b-read instr = 32 consecutive 16B
//   slots = bank-balanced (conflicts measured 0 in round-7).
// Accumulation chain per (row,code) unchanged (ascending 4-dim quads,
// acc += (ax*bx + ay*by + az*bz + aw*bw), reset per kt-tile) -> bit-identical.
// Explicit s_waitcnt(0) before each barrier (round-6 race fix, proven).
#define BM 64

__global__ __launch_bounds__(256)
__attribute__((amdgpu_waves_per_eu(4, 4)))
void vq_argmin_kernel(const float* __restrict__ x, const float* __restrict__ emb,
                      const float* __restrict__ c, const float* __restrict__ x2g,
                      float* __restrict__ idx_f, unsigned* __restrict__ counts) {
    extern __shared__ float smem[];          // 16384 B
    float* Bsl = smem;                       // 4096 floats (2 bufs x 2048), buf = [g:2][code:256][4]

    const int tid  = threadIdx.x;
    const int tx   = tid & 31, ty = tid >> 5;
    const int wave = tid >> 6, lane = tid & 63;
    const int row0 = blockIdx.x * BM;

    const float4* x4 = (const float4*)x;
    const float4* e4 = (const float4*)emb;

    // per-thread A base: rows ty*8 .. ty*8+7 of this block's tile
    const float4* ar = x4 + ((size_t)(row0 + ty * 8) * 64);

    // ---- B DMA step 0 (kt=0, dims [0,8)) ----
    {
        #pragma unroll
        for (int q = 0; q < 2; ++q) {
            int idx = wave * 2 + q;              // 0..7
            int g = idx >> 2, rblk = idx & 3;
            int r = rblk * 64 + lane;            // code 0..255
            __builtin_amdgcn_global_load_lds(
                (gvoid_t*)(e4 + ((size_t)r * 64 + g)),
                (lvoid_t*)(Bsl + g * 1024 + rblk * 256), 16, 0, 0);
        }
    }

    // per-row ||x||^2 from precomputed global (same values as inline chain)
    float x2r[8];
    #pragma unroll
    for (int j = 0; j < 8; ++j) x2r[j] = x2g[row0 + ty * 8 + j];

    __builtin_amdgcn_s_waitcnt(0);           // DMA landed in LDS
    __syncthreads();

    float best[8]; int bidx[8];
    #pragma unroll
    for (int j = 0; j < 8; ++j) { best[j] = 3.4e38f; bidx[j] = 0; }

    float acc[8][8];
    #pragma unroll
    for (int j = 0; j < 8; ++j)
        #pragma unroll
        for (int i = 0; i < 8; ++i) acc[j][i] = 0.f;

    const float4* B4 = (const float4*)Bsl;

    // 256 steps = 8 kt-tiles (256 codes) x 32 dim-chunks (8 dims)
    for (int s = 0; s < 256; ++s) {
        int dc = s & 31;

        // async DMA of next B chunk into the other buffer
        if (s < 255) {
            int sn   = s + 1;
            int dcn  = sn & 31;
            int ktn  = (sn >> 5) << 8;           // code-tile base row
            int d4n  = dcn << 1;                 // dim offset in float4 units
            float* Bd = Bsl + (sn & 1) * 2048;
            #pragma unroll
            for (int q = 0; q < 2; ++q) {
                int idx = wave * 2 + q;
                int g = idx >> 2, rblk = idx & 3;
                int r = rblk * 64 + lane;
                __builtin_amdgcn_global_load_lds(
                    (gvoid_t*)(e4 + ((size_t)(ktn + r) * 64 + d4n + g)),
                    (lvoid_t*)(Bd + g * 1024 + rblk * 256), 16, 0, 0);
            }
        }

        // compute this 8-dim chunk; dims ascending -> ref-identical chain
        {
            int abase = dc << 1;                 // dim offset in float4 units
            int bbase = (s & 1) * 512 + tx;      // float4 units
            #pragma unroll
            for (int g = 0; g < 2; ++g) {
                float4 a[8], b[8];
                #pragma unroll
                for (int j = 0; j < 8; ++j) a[j] = ar[abase + j * 64 + g];   // global broadcast (2 addrs/wave)
                #pragma unroll
                for (int i = 0; i < 8; ++i) b[i] = B4[bbase + g * 256 + i * 32];
                #pragma unroll
                for (int j = 0; j < 8; ++j)
                    #pragma unroll
                    for (int i = 0; i < 8; ++i)
                        acc[j][i] += a[j].x * b[i].x + a[j].y * b[i].y
                                   + a[j].z * b[i].z + a[j].w * b[i].w;
            }
        }

        if (dc == 31) {                          // full D done for this kt tile: fold argmin
            int kt = (s >> 5) << 8;
            #pragma unroll
            for (int i = 0; i < 8; ++i) {
                int k = kt + tx + 32 * i;        // ascending in i -> lowest-index tie win
                float ck = c[k];
                #pragma unroll
                for (int j = 0; j < 8; ++j) {
                    float t = x2r[j] + ck;               // matches reference eval order
                    float dst = t - 2.0f * acc[j][i];    // *2 exact
                    if (dst < best[j]) { best[j] = dst; bidx[j] = k; }
                }
            }
            #pragma unroll
            for (int j = 0; j < 8; ++j)
                #pragma unroll
                for (int i = 0; i < 8; ++i) acc[j][i] = 0.f;
        }

        __builtin_amdgcn_s_waitcnt(0);           // next-B DMA landed; this buf's reads done
        __syncthreads();
    }

    // final reduction: 32-lane shuffle over tx (each row's 32 candidates sit in one
    // half-wave: lanes (ty&1)*32 + tx). Min with ties -> lowest index.
    #pragma unroll
    for (int j = 0; j < 8; ++j) {
        float bv = best[j]; int bi = bidx[j];
        #pragma unroll
        for (int off = 16; off > 0; off >>= 1) {
            float ov = __shfl_down(bv, off, 32);
            int   oi = __shfl_down(bi, off, 32);
            if (ov < bv || (ov == bv && oi < bi)) { bv = ov; bi = oi; }
        }
        best[j] = bv; bidx[j] = bi;
    }
    if (tx == 0) {
        #pragma unroll
        for (int j = 0; j < 8; ++j) {
            idx_f[row0 + ty * 8 + j] = (float)bidx[j];
            atomicAdd(&counts[bidx[j]], 1u);
        }
    }
}

// ---------------- gather: quantized_st = x + (e - x) (matches ST rounding), MSE sum ----------------
__global__ void vq_gather_kernel(const float* __restrict__ x, const float* __restrict__ emb,
                                 const float* __restrict__ idx_f, float* __restrict__ outq,
                                 double* __restrict__ sums) {
    __shared__ float red[256];
    int tid = threadIdx.x;
    int q = blockIdx.x * 256 + tid;        // float4 index, 4194304 total
    int n = q >> 6;
    int d4 = (q & 63) << 2;
    int k = (int)idx_f[n];                 // small ints stored exactly in f32
    float4 e  = *(const float4*)(emb + (size_t)k * DIM + d4);
    float4 xv = *(const float4*)(x + ((size_t)n * DIM + d4));
    float d0 = e.x - xv.x, d1 = e.y - xv.y, d2 = e.z - xv.z, d3 = e.w - xv.w;
    float4 o;
    o.x = xv.x + d0; o.y = xv.y + d1; o.z = xv.z + d2; o.w = xv.w + d3;
    *(float4*)(outq + (size_t)q * 4) = o;
    red[tid] = d0 * d0 + d1 * d1 + d2 * d2 + d3 * d3;
    __syncthreads();
    for (int off = 128; off > 0; off >>= 1) {
        if (tid < off) red[tid] += red[tid + off];
        __syncthreads();
    }
    if (tid == 0) atomicAdd(&sums[0], (double)red[0]);
}

// ---------------- sim: sum |off-diagonal cosine| ----------------
#define SPAD 68
__global__ __launch_bounds__(256)
void vq_sim_kernel(const float* __restrict__ emb, const float* __restrict__ invn,
                   double* __restrict__ sums) {
    __shared__ float Ai[64][SPAD];
    __shared__ float Bj[64][SPAD];
    int bi = blockIdx.x >> 5;
    int bj = blockIdx.x & 31;
    int tid = threadIdx.x;
    int tx = tid & 15, ty = tid >> 4;

    float acc[4][4];
    #pragma unroll
    for (int j = 0; j < 4; ++j)
        #pragma unroll
        for (int i = 0; i < 4; ++i) acc[j][i] = 0.f;

    for (int dc = 0; dc < DIM; dc += 64) {
        #pragma unroll
        for (int rr = 0; rr < 4; ++rr) {
            int row = rr * 16 + ty;
            int col = tx * 4;
            int ga = bi * 64 + row, gb = bj * 64 + row;
            float4 a = *(const float4*)(emb + (size_t)ga * DIM + dc + col);
            float4 b = *(const float4*)(emb + (size_t)gb * DIM + dc + col);
            float sa = invn[ga], sb = invn[gb];
            Ai[row][col + 0] = a.x * sa; Ai[row][col + 1] = a.y * sa;
            Ai[row][col + 2] = a.z * sa; Ai[row][col + 3] = a.w * sa;
            Bj[row][col + 0] = b.x * sb; Bj[row][col + 1] = b.y * sb;
            Bj[row][col + 2] = b.z * sb; Bj[row][col + 3] = b.w * sb;
        }
        __syncthreads();
        for (int d = 0; d < 64; d += 4) {
            float4 a[4], b[4];
            #pragma unroll
            for (int j = 0; j < 4; ++j) a[j] = *(const float4*)&Ai[ty * 4 + j][d];
            #pragma unroll
            for (int i = 0; i < 4; ++i) b[i] = *(const float4*)&Bj[tx * 4 + i][d];
            #pragma unroll
            for (int j = 0; j < 4; ++j)
                #pragma unroll
                for (int i = 0; i < 4; ++i)
                    acc[j][i] += a[j].x * b[i].x + a[j].y * b[i].y
                               + a[j].z * b[i].z + a[j].w * b[i].w;
        }
        __syncthreads();
    }
    float s = 0.f;
    #pragma unroll
    for (int j = 0; j < 4; ++j)
        #pragma unroll
        for (int i = 0; i < 4; ++i) {
            int gi = bi * 64 + ty * 4 + j;
            int gj = bj * 64 + tx * 4 + i;
            if (gi != gj) s += fabsf(acc[j][i]);
        }
    float* red = &Ai[0][0];
    red[tid] = s;
    __syncthreads();
    for (int off = 128; off > 0; off >>= 1) {
        if (tid < off) red[tid] += red[tid + off];
        __syncthreads();
    }
    if (tid == 0) atomicAdd(&sums[2], (double)red[0]);
}

// ---------------- finalize: KL, perplexity, total loss ----------------
__global__ void vq_finalize_kernel(const unsigned* __restrict__ counts,
                                   const double* __restrict__ sums,
                                   float* __restrict__ out_scalars) {
    __shared__ double sred[256];
    int tid = threadIdx.x;
    double t = 0.0;
    for (int k = tid; k < KCODES; k += 256) t += (double)counts[k];
    sred[tid] = t; __syncthreads();
    for (int off = 128; off > 0; off >>= 1) {
        if (tid < off) sred[tid] += sred[tid + off];
        __syncthreads();
    }
    double total = sred[0];
    __syncthreads();

    const double eps = 1e-8, tunif = 1.0 / (double)KCODES;
    double klsum = 0.0, plogpsum = 0.0;
    for (int k = tid; k < KCODES; k += 256) {
        double p = (double)counts[k] / total;
        klsum += (p + eps) * log((p + eps) / (tunif + eps));
        if (p > 0.0) plogpsum += p * log(p);
    }
    sred[tid] = klsum; __syncthreads();
    for (int off = 128; off > 0; off >>= 1) {
        if (tid < off) sred[tid] += sred[tid + off];
        __syncthreads();
    }
    klsum = sred[0];
    __syncthreads();
    sred[tid] = plogpsum; __syncthreads();
    for (int off = 128; off > 0; off >>= 1) {
        if (tid < off) sred[tid] += sred[tid + off];
        __syncthreads();
    }
    plogpsum = sred[0];

    if (tid == 0) {
        float mse = (float)(sums[0] / (double)((size_t)NROWS * DIM));
        float vq = mse + 0.25f * mse;                       // q_latent + COST*e_latent (equal in value)
        float kl = fminf((float)klsum, 100.0f);
        float l2 = fminf((float)(sums[1] / (double)KCODES), 10.0f);
        float orth = fminf((float)(sums[2] / ((double)KCODES * (double)KCODES)), 10.0f);
        float reg = l2 + orth;
        float total_loss = fminf(vq + 0.1f * kl + 0.01f * reg, 100.0f);
        out_scalars[0] = total_loss;
        out_scalars[1] = (float)exp(-plogpsum);
    }
}

extern "C" void kernel_launch(void* const* d_in, const int* in_sizes, int n_in,
                              void* d_out, int out_size, void* d_ws, size_t ws_size,
                              hipStream_t stream) {
    const float* x   = (const float*)d_in[0];   // (16,4096,256) f32
    const float* emb = (const float*)d_in[1];   // (2048,256)   f32
    float* out = (float*)d_out;

    char* ws = (char*)d_ws;
    float*    c      = (float*)(ws + WS_C);
    float*    invn   = (float*)(ws + WS_INV);
    unsigned* counts = (unsigned*)(ws + WS_COUNTS);
    double*   sums   = (double*)(ws + WS_SUMS);
    float*    x2g    = (float*)(ws + WS_X2);

    float* outq        = out;                 // quantized_st
    float* out_scalars = out + Q_OFF;         // loss, perplexity
    float* idx_f       = out + Q_OFF + 2;     // idx as float

    vq_init_kernel<<<1, 256, 0, stream>>>(counts, sums);
    vq_prep_kernel<<<KCODES, 64, 0, stream>>>(emb, c, invn, sums);
    vq_x2_kernel<<<NROWS / 256, 256, 0, stream>>>(x, x2g);
    vq_argmin_kernel<<<NROWS / BM, 256, 16384, stream>>>(x, emb, c, x2g, idx_f, counts);
    vq_gather_kernel<<<(NROWS * DIM / 4) / 256, 256, 0, stream>>>(x, emb, idx_f, outq, sums);
    vq_sim_kernel<<<(KCODES / 64) * (KCODES / 64), 256, 0, stream>>>(emb, invn, sums);
    vq_finalize_kernel<<<1, 256, 0, stream>>>(counts, sums, out_scalars);
}

// Round 3
// 1414.805 us; speedup vs baseline: 10.6480x; 10.6480x over previous
//
#include <hip/hip_runtime.h>
#include <math.h>

// Problem constants (EnhancedVectorQuantizer): inputs (16,4096,256) f32, emb (2048,256) f32
#define NROWS  65536
#define DIM    256
#define KCODES 2048

#define Q_OFF  16777216   // NROWS*DIM; d_out layout: [0,Q_OFF) quantized_st, [Q_OFF]=loss, [Q_OFF+1]=perplexity, [Q_OFF+2..) idx as f32

// workspace byte offsets (total 294912 B)
#define WS_C      0        // 2048 f32  ||e_k||^2
#define WS_INV    8192     // 2048 f32  1/max(rownorm,1e-12)
#define WS_COUNTS 16384    // 2048 u32
#define WS_SUMS   24576    // 3 doubles: [0]=mse_sum [1]=l2_sum [2]=orth_sum
#define WS_X2     32768    // 65536 f32 ||x_n||^2

typedef __attribute__((address_space(1))) const void gvoid_t;
typedef __attribute__((address_space(3))) void lvoid_t;

// ---------------- init: zero accumulators (ws is poisoned 0xAA every launch) ----------------
__global__ void vq_init_kernel(unsigned* __restrict__ counts, double* __restrict__ sums) {
    int t = threadIdx.x;
    for (int k = t; k < KCODES; k += 256) counts[k] = 0u;
    if (t < 3) sums[t] = 0.0;
}

// ---------------- prep: c[k]=||e_k||^2, inv rownorm, l2 sum ----------------
__global__ void vq_prep_kernel(const float* __restrict__ emb, float* __restrict__ c,
                               float* __restrict__ invn, double* __restrict__ sums) {
    int k = blockIdx.x;
    int lane = threadIdx.x;                       // 64 lanes
    float4 v = ((const float4*)(emb + (size_t)k * DIM))[lane];
    float s = v.x * v.x + v.y * v.y + v.z * v.z + v.w * v.w;
    #pragma unroll
    for (int off = 32; off > 0; off >>= 1) s += __shfl_down(s, off, 64);
    if (lane == 0) {
        c[k] = s;
        float rn = sqrtf(s);
        invn[k] = 1.0f / fmaxf(rn, 1e-12f);
        atomicAdd(&sums[1], (double)rn);
    }
}

// ---------------- x2: per-row ||x||^2, serial float4 chain (bit-identical to ref order) ----------------
__global__ void vq_x2_kernel(const float* __restrict__ x, float* __restrict__ x2g) {
    int row = blockIdx.x * 256 + threadIdx.x;
    const float4* xr = (const float4*)(x + (size_t)row * DIM);
    float s = 0.f;
    for (int d4 = 0; d4 < DIM / 4; ++d4) {
        float4 v = xr[d4];
        s += v.x * v.x; s += v.y * v.y; s += v.z * v.z; s += v.w * v.w;
    }
    x2g[row] = s;
}

// ---------------- argmin: barrier-free wave-private-B streamed fp32 distance GEMM ----------------
// Round-9 theory: round-7 (A+B in LDS, per-step waitcnt(0)+barrier, 2 waves/SIMD)
// measured 1212us / VALUBusy 67% / conflicts 0. VALU issue floor of the bit-exact
// stream ~874us; the 30% bubble = 256 cross-wave barrier drains + post-barrier LDS
// latency with only 2 waves/SIMD of cover. Round-8's global-A variant spilled acc
// to scratch (VGPR 64, 45GB scratch writes, 14.3ms) -> reverted; A stays in LDS,
// waves_per_eu(2,2) stays.
// Fix here: BARRIER-FREE K-loop. Each wave owns 64 CODES x all 64 rows of the
// kt-tile and double-buffers its own private 2KB B chunk (4 waves x 2 x 2KB = 16KB).
// The only loop-carried dependency is within-wave (own global_load_lds -> own
// ds_read), enforced by s_waitcnt vmcnt(0)-via-builtin + sched_barrier at the top
// of each step. No s_barrier in the 256-step loop (one after the A prologue, one
// before the final cross-wave merge). Waves free-run; compiler pipelines across steps.
//   threads: lane = (row_h:3)(cq:3) within wave; thread tile = 8 rows x 8 codes
//     rows  = row_h*8 + j           (j = 0..7)
//     codes = kt + wave*64 + cq + 8*i  (i = 0..7, ascending -> lowest-tie wins)
//   A layout (64KB): [dk:4][row:64][slot:16][float4], slot = chunk ^ ((row>>3)&7).
//     a-read: 8 distinct rows (row_h=0..7) at 2KB stride -> same bank quad unswizzled;
//     the row_h-keyed XOR spreads them over 8 distinct quads -> conflict-free.
//     DMA dest linear (1KB/instr = 4 rows x 16 slots); source chunk pre-swizzled:
//     cc = (lane&15) ^ ((seg>>1)&7)   (m173 pattern: swizzle the global address).
//   B wave chunk (2KB): [g:2][code:64][float4]; b-read = 8 addrs 16B apart ->
//     8 distinct quads, conflict-free. DMA: 2 instrs/step, per-lane source row.
// Accumulation chain per (row,code) textually identical to round-7 (ascending 4-dim
// quads, acc += ax*bx + ay*by + az*bz + aw*bw, reset per kt-tile; dist = (x2+c) - 2*acc)
// -> bit-exact.
#define BM 64

__global__ __launch_bounds__(256)
__attribute__((amdgpu_waves_per_eu(2, 2)))
void vq_argmin_kernel(const float* __restrict__ x, const float* __restrict__ emb,
                      const float* __restrict__ c, const float* __restrict__ x2g,
                      float* __restrict__ idx_f, unsigned* __restrict__ counts) {
    extern __shared__ float smem[];          // 81920 B
    float* Asl = smem;                       // 16384 floats (64 KB)
    float* Bsl = smem + 16384;               // 4096 floats (16 KB): [wave:4][buf:2][g:2][code:64][4]

    const int tid   = threadIdx.x;
    const int wave  = tid >> 6, lane = tid & 63;
    const int row_h = lane >> 3;             // 0..7: row group
    const int cq    = lane & 7;              // 0..7: code sub-index
    const int row0  = blockIdx.x * BM;

    const float4* x4 = (const float4*)x;
    const float4* e4 = (const float4*)emb;

    // ---- A DMA (once): linear dest, source-swizzled; 16 instrs/wave ----
    #pragma unroll
    for (int dk = 0; dk < 4; ++dk)
        #pragma unroll
        for (int q = 0; q < 4; ++q) {
            int sg = wave + 4 * q;                       // segment 0..15 (4 rows each)
            int rsub = lane >> 4;                        // 0..3
            int row  = sg * 4 + rsub;
            int cc   = (lane & 15) ^ ((sg >> 1) & 7);    // (row>>3)&7 == (sg>>1)&7
            __builtin_amdgcn_global_load_lds(
                (gvoid_t*)(x4 + ((size_t)(row0 + row) * 64 + dk * 16 + cc)),
                (lvoid_t*)(Asl + dk * 4096 + sg * 256), 16, 0, 0);
        }

    // ---- B DMA step 0 (own 64 codes, dims [0,8)) ----
    #pragma unroll
    for (int g = 0; g < 2; ++g)
        __builtin_amdgcn_global_load_lds(
            (gvoid_t*)(e4 + ((size_t)(wave * 64 + lane) * 64 + g)),
            (lvoid_t*)(Bsl + wave * 1024 + g * 256), 16, 0, 0);

    // per-row ||x||^2 (rows row_h*8+j)
    float x2r[8];
    #pragma unroll
    for (int j = 0; j < 8; ++j) x2r[j] = x2g[row0 + row_h * 8 + j];

    __builtin_amdgcn_s_waitcnt(0);           // A + B0 landed
    __syncthreads();                         // A visible to all waves (only loop-entry barrier)

    float best[8]; int bidx[8];
    #pragma unroll
    for (int j = 0; j < 8; ++j) { best[j] = 3.4e38f; bidx[j] = 0; }

    float acc[8][8];
    #pragma unroll
    for (int j = 0; j < 8; ++j)
        #pragma unroll
        for (int i = 0; i < 8; ++i) acc[j][i] = 0.f;

    const char* AsB = (const char*)Asl;
    const char* BsB = (const char*)Bsl;

    // 256 steps = 8 kt-tiles (256 codes) x 32 dim-chunks (8 dims). NO barriers.
    for (int s = 0; s < 256; ++s) {
        // own DMA from step s-1 landed; pin all LDS reads below this point
        __builtin_amdgcn_s_waitcnt(0);
        __builtin_amdgcn_sched_barrier(0);

        // issue own next-step DMA into the other private buffer
        if (s < 255) {
            int sn  = s + 1;
            int ktn = (sn >> 5) << 8;
            int d4n = (sn & 31) << 1;
            float* Bd = Bsl + wave * 1024 + (sn & 1) * 512;
            #pragma unroll
            for (int g = 0; g < 2; ++g)
                __builtin_amdgcn_global_load_lds(
                    (gvoid_t*)(e4 + ((size_t)(ktn + wave * 64 + lane) * 64 + d4n + g)),
                    (lvoid_t*)(Bd + g * 256), 16, 0, 0);
        }

        // compute this 8-dim chunk; dims ascending -> ref-identical chain
        int dc = s & 31;
        int dk = dc >> 3;                        // = (dc*2)>>4, g-invariant
        int bbyte = wave * 4096 + (s & 1) * 2048 + cq * 16;
        #pragma unroll
        for (int g = 0; g < 2; ++g) {
            int sl = (((dc << 1) + g) & 15) ^ row_h;
            int abyte = dk * 16384 + row_h * 2048 + (sl << 4);
            float4 a[8], b[8];
            #pragma unroll
            for (int j = 0; j < 8; ++j) a[j] = *(const float4*)(AsB + abyte + j * 256);
            #pragma unroll
            for (int i = 0; i < 8; ++i) b[i] = *(const float4*)(BsB + bbyte + g * 1024 + i * 128);
            #pragma unroll
            for (int j = 0; j < 8; ++j)
                #pragma unroll
                for (int i = 0; i < 8; ++i)
                    acc[j][i] += a[j].x * b[i].x + a[j].y * b[i].y
                               + a[j].z * b[i].z + a[j].w * b[i].w;
        }

        if (dc == 31) {                          // full D done for this kt tile: fold argmin
            int kt = (s >> 5) << 8;
            #pragma unroll
            for (int i = 0; i < 8; ++i) {
                int k = kt + wave * 64 + cq + 8 * i;     // ascending in i
                float ck = c[k];
                #pragma unroll
                for (int j = 0; j < 8; ++j) {
                    float t = x2r[j] + ck;               // matches reference eval order
                    float dst = t - 2.0f * acc[j][i];    // *2 exact
                    if (dst < best[j]) { best[j] = dst; bidx[j] = k; }
                }
            }
            #pragma unroll
            for (int j = 0; j < 8; ++j)
                #pragma unroll
                for (int i = 0; i < 8; ++i) acc[j][i] = 0.f;
        }
    }

    // in-wave reduce: row r's 8 candidates live in lanes row_h*8 + (0..7)
    #pragma unroll
    for (int j = 0; j < 8; ++j) {
        float bv = best[j]; int bi = bidx[j];
        #pragma unroll
        for (int off = 4; off > 0; off >>= 1) {
            float ov = __shfl_xor(bv, off, 64);          // stays within 8-lane group
            int   oi = __shfl_xor(bi, off, 64);
            if (ov < bv || (ov == bv && oi < bi)) { bv = ov; bi = oi; }
        }
        best[j] = bv; bidx[j] = bi;
    }
    // stash per-wave winners in OWN (dead) buf0 region: [0..63] val, [64..127] idx
    if (cq == 0) {
        float* stv = Bsl + wave * 1024;
        int*   sti = (int*)(Bsl + wave * 1024 + 64);
        #pragma unroll
        for (int j = 0; j < 8; ++j) {
            stv[row_h * 8 + j] = best[j];
            sti[row_h * 8 + j] = bidx[j];
        }
    }
    __builtin_amdgcn_s_waitcnt(0);
    __syncthreads();
    if (tid < BM) {
        float bv = Bsl[tid];
        int   bi = ((const int*)(Bsl + 64))[tid];
        #pragma unroll
        for (int w = 1; w < 4; ++w) {
            float v  = Bsl[w * 1024 + tid];
            int   ii = ((const int*)(Bsl + w * 1024 + 64))[tid];
            if (v < bv || (v == bv && ii < bi)) { bv = v; bi = ii; }  // ties -> lowest index
        }
        idx_f[row0 + tid] = (float)bi;
        atomicAdd(&counts[bi], 1u);
    }
}

// ---------------- gather: quantized_st = x + (e - x) (matches ST rounding), MSE sum ----------------
__global__ void vq_gather_kernel(const float* __restrict__ x, const float* __restrict__ emb,
                                 const float* __restrict__ idx_f, float* __restrict__ outq,
                                 double* __restrict__ sums) {
    __shared__ float red[256];
    int tid = threadIdx.x;
    int q = blockIdx.x * 256 + tid;        // float4 index, 4194304 total
    int n = q >> 6;
    int d4 = (q & 63) << 2;
    int k = (int)idx_f[n];                 // small ints stored exactly in f32
    float4 e  = *(const float4*)(emb + (size_t)k * DIM + d4);
    float4 xv = *(const float4*)(x + ((size_t)n * DIM + d4));
    float d0 = e.x - xv.x, d1 = e.y - xv.y, d2 = e.z - xv.z, d3 = e.w - xv.w;
    float4 o;
    o.x = xv.x + d0; o.y = xv.y + d1; o.z = xv.z + d2; o.w = xv.w + d3;
    *(float4*)(outq + (size_t)q * 4) = o;
    red[tid] = d0 * d0 + d1 * d1 + d2 * d2 + d3 * d3;
    __syncthreads();
    for (int off = 128; off > 0; off >>= 1) {
        if (tid < off) red[tid] += red[tid + off];
        __syncthreads();
    }
    if (tid == 0) atomicAdd(&sums[0], (double)red[0]);
}

// ---------------- sim: sum |off-diagonal cosine| ----------------
#define SPAD 68
__global__ __launch_bounds__(256)
void vq_sim_kernel(const float* __restrict__ emb, const float* __restrict__ invn,
                   double* __restrict__ sums) {
    __shared__ float Ai[64][SPAD];
    __shared__ float Bj[64][SPAD];
    int bi = blockIdx.x >> 5;
    int bj = blockIdx.x & 31;
    int tid = threadIdx.x;
    int tx = tid & 15, ty = tid >> 4;

    float acc[4][4];
    #pragma unroll
    for (int j = 0; j < 4; ++j)
        #pragma unroll
        for (int i = 0; i < 4; ++i) acc[j][i] = 0.f;

    for (int dc = 0; dc < DIM; dc += 64) {
        #pragma unroll
        for (int rr = 0; rr < 4; ++rr) {
            int row = rr * 16 + ty;
            int col = tx * 4;
            int ga = bi * 64 + row, gb = bj * 64 + row;
            float4 a = *(const float4*)(emb + (size_t)ga * DIM + dc + col);
            float4 b = *(const float4*)(emb + (size_t)gb * DIM + dc + col);
            float sa = invn[ga], sb = invn[gb];
            Ai[row][col + 0] = a.x * sa; Ai[row][col + 1] = a.y * sa;
            Ai[row][col + 2] = a.z * sa; Ai[row][col + 3] = a.w * sa;
            Bj[row][col + 0] = b.x * sb; Bj[row][col + 1] = b.y * sb;
            Bj[row][col + 2] = b.z * sb; Bj[row][col + 3] = b.w * sb;
        }
        __syncthreads();
        for (int d = 0; d < 64; d += 4) {
            float4 a[4], b[4];
            #pragma unroll
            for (int j = 0; j < 4; ++j) a[j] = *(const float4*)&Ai[ty * 4 + j][d];
            #pragma unroll
            for (int i = 0; i < 4; ++i) b[i] = *(const float4*)&Bj[tx * 4 + i][d];
            #pragma unroll
            for (int j = 0; j < 4; ++j)
                #pragma unroll
                for (int i = 0; i < 4; ++i)
                    acc[j][i] += a[j].x * b[i].x + a[j].y * b[i].y
                               + a[j].z * b[i].z + a[j].w * b[i].w;
        }
        __syncthreads();
    }
    float s = 0.f;
    #pragma unroll
    for (int j = 0; j < 4; ++j)
        #pragma unroll
        for (int i = 0; i < 4; ++i) {
            int gi = bi * 64 + ty * 4 + j;
            int gj = bj * 64 + tx * 4 + i;
            if (gi != gj) s += fabsf(acc[j][i]);
        }
    float* red = &Ai[0][0];
    red[tid] = s;
    __syncthreads();
    for (int off = 128; off > 0; off >>= 1) {
        if (tid < off) red[tid] += red[tid + off];
        __syncthreads();
    }
    if (tid == 0) atomicAdd(&sums[2], (double)red[0]);
}

// ---------------- finalize: KL, perplexity, total loss ----------------
__global__ void vq_finalize_kernel(const unsigned* __restrict__ counts,
                                   const double* __restrict__ sums,
                                   float* __restrict__ out_scalars) {
    __shared__ double sred[256];
    int tid = threadIdx.x;
    double t = 0.0;
    for (int k = tid; k < KCODES; k += 256) t += (double)counts[k];
    sred[tid] = t; __syncthreads();
    for (int off = 128; off > 0; off >>= 1) {
        if (tid < off) sred[tid] += sred[tid + off];
        __syncthreads();
    }
    double total = sred[0];
    __syncthreads();

    const double eps = 1e-8, tunif = 1.0 / (double)KCODES;
    double klsum = 0.0, plogpsum = 0.0;
    for (int k = tid; k < KCODES; k += 256) {
        double p = (double)counts[k] / total;
        klsum += (p + eps) * log((p + eps) / (tunif + eps));
        if (p > 0.0) plogpsum += p * log(p);
    }
    sred[tid] = klsum; __syncthreads();
    for (int off = 128; off > 0; off >>= 1) {
        if (tid < off) sred[tid] += sred[tid + off];
        __syncthreads();
    }
    klsum = sred[0];
    __syncthreads();
    sred[tid] = plogpsum; __syncthreads();
    for (int off = 128; off > 0; off >>= 1) {
        if (tid < off) sred[tid] += sred[tid + off];
        __syncthreads();
    }
    plogpsum = sred[0];

    if (tid == 0) {
        float mse = (float)(sums[0] / (double)((size_t)NROWS * DIM));
        float vq = mse + 0.25f * mse;                       // q_latent + COST*e_latent (equal in value)
        float kl = fminf((float)klsum, 100.0f);
        float l2 = fminf((float)(sums[1] / (double)KCODES), 10.0f);
        float orth = fminf((float)(sums[2] / ((double)KCODES * (double)KCODES)), 10.0f);
        float reg = l2 + orth;
        float total_loss = fminf(vq + 0.1f * kl + 0.01f * reg, 100.0f);
        out_scalars[0] = total_loss;
        out_scalars[1] = (float)exp(-plogpsum);
    }
}

extern "C" void kernel_launch(void* const* d_in, const int* in_sizes, int n_in,
                              void* d_out, int out_size, void* d_ws, size_t ws_size,
                              hipStream_t stream) {
    const float* x   = (const float*)d_in[0];   // (16,4096,256) f32
    const float* emb = (const float*)d_in[1];   // (2048,256)   f32
    float* out = (float*)d_out;

    char* ws = (char*)d_ws;
    float*    c      = (float*)(ws + WS_C);
    float*    invn   = (float*)(ws + WS_INV);
    unsigned* counts = (unsigned*)(ws + WS_COUNTS);
    double*   sums   = (double*)(ws + WS_SUMS);
    float*    x2g    = (float*)(ws + WS_X2);

    float* outq        = out;                 // quantized_st
    float* out_scalars = out + Q_OFF;         // loss, perplexity
    float* idx_f       = out + Q_OFF + 2;     // idx as float

    vq_init_kernel<<<1, 256, 0, stream>>>(counts, sums);
    vq_prep_kernel<<<KCODES, 64, 0, stream>>>(emb, c, invn, sums);
    vq_x2_kernel<<<NROWS / 256, 256, 0, stream>>>(x, x2g);
    vq_argmin_kernel<<<NROWS / BM, 256, 81920, stream>>>(x, emb, c, x2g, idx_f, counts);
    vq_gather_kernel<<<(NROWS * DIM / 4) / 256, 256, 0, stream>>>(x, emb, idx_f, outq, sums);
    vq_sim_kernel<<<(KCODES / 64) * (KCODES / 64), 256, 0, stream>>>(emb, invn, sums);
    vq_finalize_kernel<<<1, 256, 0, stream>>>(counts, sums, out_scalars);
}

// Round 4
// 1398.088 us; speedup vs baseline: 10.7753x; 1.0120x over previous
//
#include <hip/hip_runtime.h>
#include <math.h>

// Problem constants (EnhancedVectorQuantizer): inputs (16,4096,256) f32, emb (2048,256) f32
#define NROWS  65536
#define DIM    256
#define KCODES 2048

#define Q_OFF  16777216   // NROWS*DIM; d_out layout: [0,Q_OFF) quantized_st, [Q_OFF]=loss, [Q_OFF+1]=perplexity, [Q_OFF+2..) idx as f32

// workspace byte offsets (total 294912 B)
#define WS_C      0        // 2048 f32  ||e_k||^2
#define WS_INV    8192     // 2048 f32  1/max(rownorm,1e-12)
#define WS_COUNTS 16384    // 2048 u32
#define WS_SUMS   24576    // 3 doubles: [0]=mse_sum [1]=l2_sum [2]=orth_sum
#define WS_X2     32768    // 65536 f32 ||x_n||^2

typedef __attribute__((address_space(1))) const void gvoid_t;
typedef __attribute__((address_space(3))) void lvoid_t;

// ---------------- init: zero accumulators (ws is poisoned 0xAA every launch) ----------------
__global__ void vq_init_kernel(unsigned* __restrict__ counts, double* __restrict__ sums) {
    int t = threadIdx.x;
    for (int k = t; k < KCODES; k += 256) counts[k] = 0u;
    if (t < 3) sums[t] = 0.0;
}

// ---------------- prep: c[k]=||e_k||^2, inv rownorm, l2 sum ----------------
__global__ void vq_prep_kernel(const float* __restrict__ emb, float* __restrict__ c,
                               float* __restrict__ invn, double* __restrict__ sums) {
    int k = blockIdx.x;
    int lane = threadIdx.x;                       // 64 lanes
    float4 v = ((const float4*)(emb + (size_t)k * DIM))[lane];
    float s = v.x * v.x + v.y * v.y + v.z * v.z + v.w * v.w;
    #pragma unroll
    for (int off = 32; off > 0; off >>= 1) s += __shfl_down(s, off, 64);
    if (lane == 0) {
        c[k] = s;
        float rn = sqrtf(s);
        invn[k] = 1.0f / fmaxf(rn, 1e-12f);
        atomicAdd(&sums[1], (double)rn);
    }
}

// ---------------- x2: per-row ||x||^2, serial float4 chain (bit-identical to ref order) ----------------
__global__ void vq_x2_kernel(const float* __restrict__ x, float* __restrict__ x2g) {
    int row = blockIdx.x * 256 + threadIdx.x;
    const float4* xr = (const float4*)(x + (size_t)row * DIM);
    float s = 0.f;
    for (int d4 = 0; d4 < DIM / 4; ++d4) {
        float4 v = xr[d4];
        s += v.x * v.x; s += v.y * v.y; s += v.z * v.z; s += v.w * v.w;
    }
    x2g[row] = s;
}

// ---------------- argmin: barrier-free + half-step register-pipelined distance GEMM ----------------
// Round-10 theory: round-9 (barrier-free) hit 1151us, VALUBusy 72.7%; measured busy
// (837us) = 96% of the locked 8-op chain's issue floor (874us). VALU work is minimal
// and numerics-locked (no FMA contraction allowed; pk_f32 is half-rate on CDNA4).
// Remaining 280us = step-boundary LDS-latency bubbles (reads issued then immediately
// consumed) with only 2 waves/SIMD of cover.
// Fix: counted half-step register pipeline (T3/T4 adapted):
//   region 1: issue next-B DMA (+ c[k] prefetch at dc==0); issue g1 B-frag ds_reads -> b1
//   region 2: g0 math (covers b1 latency)
//   region 3: s_waitcnt vmcnt(0) ONLY (DMA issued ~1000cyc ago -> free) + sched_barrier;
//             issue NEXT step's g0 B-frag ds_reads -> b0 (buffer just landed)
//   region 4: g1 math (covers b0 latency) + argmin fold (dc==31, uses prefetched ck)
// sched_barrier(0) pins region boundaries (rule #18: builtins don't order ds_reads).
// A-reads stay region-local transients. Layouts/DMA/chain/fold/tie rules are verbatim
// round-9 -> bit-exact. LDS 80KB, 2 blocks/CU, waves_per_eu(2,2).
//   threads: lane = (row_h:3)(cq:3); thread tile = 8 rows x 8 codes
//   A layout (64KB): [dk:4][row:64][slot:16][float4], slot = chunk ^ ((row>>3)&7);
//     DMA dest linear, source pre-swizzled (proven conflict-free, measured 0)
//   B wave chunk (2KB): [g:2][code:64][float4], wave-private double buffer
#define BM 64

__global__ __launch_bounds__(256)
__attribute__((amdgpu_waves_per_eu(2, 2)))
void vq_argmin_kernel(const float* __restrict__ x, const float* __restrict__ emb,
                      const float* __restrict__ c, const float* __restrict__ x2g,
                      float* __restrict__ idx_f, unsigned* __restrict__ counts) {
    extern __shared__ float smem[];          // 81920 B
    float* Asl = smem;                       // 16384 floats (64 KB)
    float* Bsl = smem + 16384;               // 4096 floats (16 KB): [wave:4][buf:2][g:2][code:64][4]

    const int tid   = threadIdx.x;
    const int wave  = tid >> 6, lane = tid & 63;
    const int row_h = lane >> 3;             // 0..7: row group
    const int cq    = lane & 7;              // 0..7: code sub-index
    const int row0  = blockIdx.x * BM;

    const float4* x4 = (const float4*)x;
    const float4* e4 = (const float4*)emb;

    // ---- A DMA (once): linear dest, source-swizzled; 16 instrs/wave ----
    #pragma unroll
    for (int dk = 0; dk < 4; ++dk)
        #pragma unroll
        for (int q = 0; q < 4; ++q) {
            int sg = wave + 4 * q;                       // segment 0..15 (4 rows each)
            int rsub = lane >> 4;                        // 0..3
            int row  = sg * 4 + rsub;
            int cc   = (lane & 15) ^ ((sg >> 1) & 7);    // (row>>3)&7 == (sg>>1)&7
            __builtin_amdgcn_global_load_lds(
                (gvoid_t*)(x4 + ((size_t)(row0 + row) * 64 + dk * 16 + cc)),
                (lvoid_t*)(Asl + dk * 4096 + sg * 256), 16, 0, 0);
        }

    // ---- B DMA step 0 (own 64 codes, dims [0,8)) ----
    #pragma unroll
    for (int g = 0; g < 2; ++g)
        __builtin_amdgcn_global_load_lds(
            (gvoid_t*)(e4 + ((size_t)(wave * 64 + lane) * 64 + g)),
            (lvoid_t*)(Bsl + wave * 1024 + g * 256), 16, 0, 0);

    // per-row ||x||^2 (rows row_h*8+j)
    float x2r[8];
    #pragma unroll
    for (int j = 0; j < 8; ++j) x2r[j] = x2g[row0 + row_h * 8 + j];

    __builtin_amdgcn_s_waitcnt(0);           // A + B0 landed
    __syncthreads();                         // A visible to all waves (only loop-entry barrier)

    float best[8]; int bidx[8];
    #pragma unroll
    for (int j = 0; j < 8; ++j) { best[j] = 3.4e38f; bidx[j] = 0; }

    float acc[8][8];
    #pragma unroll
    for (int j = 0; j < 8; ++j)
        #pragma unroll
        for (int i = 0; i < 8; ++i) acc[j][i] = 0.f;

    const char* AsB = (const char*)Asl;
    const char* BsB = (const char*)Bsl;

    // pipelined B fragments + prefetched c values
    float4 b0[8], b1[8];
    float  ckr[8];

    // prologue: fill b0 with (s=0, g0) fragments
    {
        int bb = wave * 4096 + cq * 16;
        #pragma unroll
        for (int i = 0; i < 8; ++i) b0[i] = *(const float4*)(BsB + bb + i * 128);
    }

    // 256 steps = 8 kt-tiles (256 codes) x 32 dim-chunks (8 dims). NO barriers.
    for (int s = 0; s < 256; ++s) {
        const int dc = s & 31;
        const int bbyte = wave * 4096 + (s & 1) * 2048 + cq * 16;

        // ---- region 1: issue next DMA, c-prefetch, g1 B-frag reads ----
        if (s < 255) {
            int sn  = s + 1;
            int ktn = (sn >> 5) << 8;
            int d4n = (sn & 31) << 1;
            float* Bd = Bsl + wave * 1024 + (sn & 1) * 512;
            #pragma unroll
            for (int g = 0; g < 2; ++g)
                __builtin_amdgcn_global_load_lds(
                    (gvoid_t*)(e4 + ((size_t)(ktn + wave * 64 + lane) * 64 + d4n + g)),
                    (lvoid_t*)(Bd + g * 256), 16, 0, 0);
        }
        if (dc == 0) {
            int kt = (s >> 5) << 8;
            #pragma unroll
            for (int i = 0; i < 8; ++i) ckr[i] = c[kt + wave * 64 + cq + 8 * i];
        }
        #pragma unroll
        for (int i = 0; i < 8; ++i) b1[i] = *(const float4*)(BsB + bbyte + 1024 + i * 128);
        __builtin_amdgcn_sched_barrier(0);

        // ---- region 2: g0 math (covers b1 read latency) ----
        {
            int sl0 = ((dc << 1) & 15) ^ row_h;
            int abyte0 = (dc >> 3) * 16384 + row_h * 2048 + (sl0 << 4);
            float4 a[8];
            #pragma unroll
            for (int j = 0; j < 8; ++j) a[j] = *(const float4*)(AsB + abyte0 + j * 256);
            #pragma unroll
            for (int j = 0; j < 8; ++j)
                #pragma unroll
                for (int i = 0; i < 8; ++i)
                    acc[j][i] += a[j].x * b0[i].x + a[j].y * b0[i].y
                               + a[j].z * b0[i].z + a[j].w * b0[i].w;
        }
        __builtin_amdgcn_sched_barrier(0);

        // ---- region 3: vmcnt(0)-only wait; next step's g0 B-frag reads ----
        if (s < 255) {
            __builtin_amdgcn_s_waitcnt(0x0F70);      // vmcnt(0), lgkm/exp unconstrained
            __builtin_amdgcn_sched_barrier(0);
            int bbn = wave * 4096 + ((s + 1) & 1) * 2048 + cq * 16;
            #pragma unroll
            for (int i = 0; i < 8; ++i) b0[i] = *(const float4*)(BsB + bbn + i * 128);
        }
        __builtin_amdgcn_sched_barrier(0);

        // ---- region 4: g1 math (covers b0 read latency) + fold ----
        {
            int sl1 = (((dc << 1) + 1) & 15) ^ row_h;
            int abyte1 = (dc >> 3) * 16384 + row_h * 2048 + (sl1 << 4);
            float4 a[8];
            #pragma unroll
            for (int j = 0; j < 8; ++j) a[j] = *(const float4*)(AsB + abyte1 + j * 256);
            #pragma unroll
            for (int j = 0; j < 8; ++j)
                #pragma unroll
                for (int i = 0; i < 8; ++i)
                    acc[j][i] += a[j].x * b1[i].x + a[j].y * b1[i].y
                               + a[j].z * b1[i].z + a[j].w * b1[i].w;
        }
        if (dc == 31) {                          // full D done for this kt tile: fold argmin
            int kt = (s >> 5) << 8;
            #pragma unroll
            for (int i = 0; i < 8; ++i) {
                int k = kt + wave * 64 + cq + 8 * i;     // ascending in i
                #pragma unroll
                for (int j = 0; j < 8; ++j) {
                    float t = x2r[j] + ckr[i];           // matches reference eval order
                    float dst = t - 2.0f * acc[j][i];    // *2 exact
                    if (dst < best[j]) { best[j] = dst; bidx[j] = k; }
                }
            }
            #pragma unroll
            for (int j = 0; j < 8; ++j)
                #pragma unroll
                for (int i = 0; i < 8; ++i) acc[j][i] = 0.f;
        }
    }

    // in-wave reduce: row r's 8 candidates live in lanes row_h*8 + (0..7)
    #pragma unroll
    for (int j = 0; j < 8; ++j) {
        float bv = best[j]; int bi = bidx[j];
        #pragma unroll
        for (int off = 4; off > 0; off >>= 1) {
            float ov = __shfl_xor(bv, off, 64);          // stays within 8-lane group
            int   oi = __shfl_xor(bi, off, 64);
            if (ov < bv || (ov == bv && oi < bi)) { bv = ov; bi = oi; }
        }
        best[j] = bv; bidx[j] = bi;
    }
    // stash per-wave winners in OWN (dead) buf0 region: [0..63] val, [64..127] idx
    if (cq == 0) {
        float* stv = Bsl + wave * 1024;
        int*   sti = (int*)(Bsl + wave * 1024 + 64);
        #pragma unroll
        for (int j = 0; j < 8; ++j) {
            stv[row_h * 8 + j] = best[j];
            sti[row_h * 8 + j] = bidx[j];
        }
    }
    __builtin_amdgcn_s_waitcnt(0);
    __syncthreads();
    if (tid < BM) {
        float bv = Bsl[tid];
        int   bi = ((const int*)(Bsl + 64))[tid];
        #pragma unroll
        for (int w = 1; w < 4; ++w) {
            float v  = Bsl[w * 1024 + tid];
            int   ii = ((const int*)(Bsl + w * 1024 + 64))[tid];
            if (v < bv || (v == bv && ii < bi)) { bv = v; bi = ii; }  // ties -> lowest index
        }
        idx_f[row0 + tid] = (float)bi;
        atomicAdd(&counts[bi], 1u);
    }
}

// ---------------- gather: quantized_st = x + (e - x) (matches ST rounding), MSE sum ----------------
__global__ void vq_gather_kernel(const float* __restrict__ x, const float* __restrict__ emb,
                                 const float* __restrict__ idx_f, float* __restrict__ outq,
                                 double* __restrict__ sums) {
    __shared__ float red[256];
    int tid = threadIdx.x;
    int q = blockIdx.x * 256 + tid;        // float4 index, 4194304 total
    int n = q >> 6;
    int d4 = (q & 63) << 2;
    int k = (int)idx_f[n];                 // small ints stored exactly in f32
    float4 e  = *(const float4*)(emb + (size_t)k * DIM + d4);
    float4 xv = *(const float4*)(x + ((size_t)n * DIM + d4));
    float d0 = e.x - xv.x, d1 = e.y - xv.y, d2 = e.z - xv.z, d3 = e.w - xv.w;
    float4 o;
    o.x = xv.x + d0; o.y = xv.y + d1; o.z = xv.z + d2; o.w = xv.w + d3;
    *(float4*)(outq + (size_t)q * 4) = o;
    red[tid] = d0 * d0 + d1 * d1 + d2 * d2 + d3 * d3;
    __syncthreads();
    for (int off = 128; off > 0; off >>= 1) {
        if (tid < off) red[tid] += red[tid + off];
        __syncthreads();
    }
    if (tid == 0) atomicAdd(&sums[0], (double)red[0]);
}

// ---------------- sim: sum |off-diagonal cosine| ----------------
#define SPAD 68
__global__ __launch_bounds__(256)
void vq_sim_kernel(const float* __restrict__ emb, const float* __restrict__ invn,
                   double* __restrict__ sums) {
    __shared__ float Ai[64][SPAD];
    __shared__ float Bj[64][SPAD];
    int bi = blockIdx.x >> 5;
    int bj = blockIdx.x & 31;
    int tid = threadIdx.x;
    int tx = tid & 15, ty = tid >> 4;

    float acc[4][4];
    #pragma unroll
    for (int j = 0; j < 4; ++j)
        #pragma unroll
        for (int i = 0; i < 4; ++i) acc[j][i] = 0.f;

    for (int dc = 0; dc < DIM; dc += 64) {
        #pragma unroll
        for (int rr = 0; rr < 4; ++rr) {
            int row = rr * 16 + ty;
            int col = tx * 4;
            int ga = bi * 64 + row, gb = bj * 64 + row;
            float4 a = *(const float4*)(emb + (size_t)ga * DIM + dc + col);
            float4 b = *(const float4*)(emb + (size_t)gb * DIM + dc + col);
            float sa = invn[ga], sb = invn[gb];
            Ai[row][col + 0] = a.x * sa; Ai[row][col + 1] = a.y * sa;
            Ai[row][col + 2] = a.z * sa; Ai[row][col + 3] = a.w * sa;
            Bj[row][col + 0] = b.x * sb; Bj[row][col + 1] = b.y * sb;
            Bj[row][col + 2] = b.z * sb; Bj[row][col + 3] = b.w * sb;
        }
        __syncthreads();
        for (int d = 0; d < 64; d += 4) {
            float4 a[4], b[4];
            #pragma unroll
            for (int j = 0; j < 4; ++j) a[j] = *(const float4*)&Ai[ty * 4 + j][d];
            #pragma unroll
            for (int i = 0; i < 4; ++i) b[i] = *(const float4*)&Bj[tx * 4 + i][d];
            #pragma unroll
            for (int j = 0; j < 4; ++j)
                #pragma unroll
                for (int i = 0; i < 4; ++i)
                    acc[j][i] += a[j].x * b[i].x + a[j].y * b[i].y
                               + a[j].z * b[i].z + a[j].w * b[i].w;
        }
        __syncthreads();
    }
    float s = 0.f;
    #pragma unroll
    for (int j = 0; j < 4; ++j)
        #pragma unroll
        for (int i = 0; i < 4; ++i) {
            int gi = bi * 64 + ty * 4 + j;
            int gj = bj * 64 + tx * 4 + i;
            if (gi != gj) s += fabsf(acc[j][i]);
        }
    float* red = &Ai[0][0];
    red[tid] = s;
    __syncthreads();
    for (int off = 128; off > 0; off >>= 1) {
        if (tid < off) red[tid] += red[tid + off];
        __syncthreads();
    }
    if (tid == 0) atomicAdd(&sums[2], (double)red[0]);
}

// ---------------- finalize: KL, perplexity, total loss ----------------
__global__ void vq_finalize_kernel(const unsigned* __restrict__ counts,
                                   const double* __restrict__ sums,
                                   float* __restrict__ out_scalars) {
    __shared__ double sred[256];
    int tid = threadIdx.x;
    double t = 0.0;
    for (int k = tid; k < KCODES; k += 256) t += (double)counts[k];
    sred[tid] = t; __syncthreads();
    for (int off = 128; off > 0; off >>= 1) {
        if (tid < off) sred[tid] += sred[tid + off];
        __syncthreads();
    }
    double total = sred[0];
    __syncthreads();

    const double eps = 1e-8, tunif = 1.0 / (double)KCODES;
    double klsum = 0.0, plogpsum = 0.0;
    for (int k = tid; k < KCODES; k += 256) {
        double p = (double)counts[k] / total;
        klsum += (p + eps) * log((p + eps) / (tunif + eps));
        if (p > 0.0) plogpsum += p * log(p);
    }
    sred[tid] = klsum; __syncthreads();
    for (int off = 128; off > 0; off >>= 1) {
        if (tid < off) sred[tid] += sred[tid + off];
        __syncthreads();
    }
    klsum = sred[0];
    __syncthreads();
    sred[tid] = plogpsum; __syncthreads();
    for (int off = 128; off > 0; off >>= 1) {
        if (tid < off) sred[tid] += sred[tid + off];
        __syncthreads();
    }
    plogpsum = sred[0];

    if (tid == 0) {
        float mse = (float)(sums[0] / (double)((size_t)NROWS * DIM));
        float vq = mse + 0.25f * mse;                       // q_latent + COST*e_latent (equal in value)
        float kl = fminf((float)klsum, 100.0f);
        float l2 = fminf((float)(sums[1] / (double)KCODES), 10.0f);
        float orth = fminf((float)(sums[2] / ((double)KCODES * (double)KCODES)), 10.0f);
        float reg = l2 + orth;
        float total_loss = fminf(vq + 0.1f * kl + 0.01f * reg, 100.0f);
        out_scalars[0] = total_loss;
        out_scalars[1] = (float)exp(-plogpsum);
    }
}

extern "C" void kernel_launch(void* const* d_in, const int* in_sizes, int n_in,
                              void* d_out, int out_size, void* d_ws, size_t ws_size,
                              hipStream_t stream) {
    const float* x   = (const float*)d_in[0];   // (16,4096,256) f32
    const float* emb = (const float*)d_in[1];   // (2048,256)   f32
    float* out = (float*)d_out;

    char* ws = (char*)d_ws;
    float*    c      = (float*)(ws + WS_C);
    float*    invn   = (float*)(ws + WS_INV);
    unsigned* counts = (unsigned*)(ws + WS_COUNTS);
    double*   sums   = (double*)(ws + WS_SUMS);
    float*    x2g    = (float*)(ws + WS_X2);

    float* outq        = out;                 // quantized_st
    float* out_scalars = out + Q_OFF;         // loss, perplexity
    float* idx_f       = out + Q_OFF + 2;     // idx as float

    vq_init_kernel<<<1, 256, 0, stream>>>(counts, sums);
    vq_prep_kernel<<<KCODES, 64, 0, stream>>>(emb, c, invn, sums);
    vq_x2_kernel<<<NROWS / 256, 256, 0, stream>>>(x, x2g);
    vq_argmin_kernel<<<NROWS / BM, 256, 81920, stream>>>(x, emb, c, x2g, idx_f, counts);
    vq_gather_kernel<<<(NROWS * DIM / 4) / 256, 256, 0, stream>>>(x, emb, idx_f, outq, sums);
    vq_sim_kernel<<<(KCODES / 64) * (KCODES / 64), 256, 0, stream>>>(emb, invn, sums);
    vq_finalize_kernel<<<1, 256, 0, stream>>>(counts, sums, out_scalars);
}